// Round 8
// baseline (4480.583 us; speedup 1.0000x reference)
//
#include <hip/hip_runtime.h>

// ---------------------------------------------------------------------------
// mLSTM epitope/antigen model, MI355X fp16-MFMA, round 14.
//
// R14 vs R13 (4.31 ms):
//  - COUNTED-VMCNT 2-BUFFER barriers in stepA/stepB. R13 still used
//    __syncthreads per group = s_waitcnt vmcnt(0) drain -> up to 16 exposed
//    latencies per stepB item. Now: raw s_barrier (no counter wait) +
//    hand-counted s_waitcnt vmcnt(N) + sched_barrier(0) fences (R10-proven
//    discipline). Per group: BAR; S(g+1); A(g+1); WAITV(n); BAR; C(g).
//    Ledger (per wave, in-order): stepB 4-chunk groups: out=16 -> W(8),
//    iter14 W(2), iter15 W(0). stepA 8-chunk groups: out=24 -> W(12),
//    iter6 W(6), iter7 W(0).
//  - launch_bounds(256,4): pins VGPR <= 128 -> 4 blocks/CU (LDS 32 KB
//    allows 5). R13's (256,2) let compiler exceed 128 silently.
//  - Everything else == R13 (proven decode, XCD-stable mapping).
// ---------------------------------------------------------------------------

typedef _Float16 f16;
typedef _Float16 half8 __attribute__((ext_vector_type(8)));
typedef float f32x4 __attribute__((ext_vector_type(4)));

#define H_    1900
#define HP    1920
#define NKA   60     // K-chunks for h/WmhS (1920/32)
#define NKB   61     // K-chunks for m/WhS (1952/32)
#define NKF   120    // K-chunks for fc1 (3840/32)
#define NR    512
#define TT    153
#define TE    25
#define EMB_  10
#define FCN   384

#define WAITV(n) do { asm volatile("s_waitcnt vmcnt(" #n ")" ::: "memory"); \
                      __builtin_amdgcn_sched_barrier(0); } while (0)
#define BARR  do { __builtin_amdgcn_s_barrier(); \
                   __builtin_amdgcn_sched_barrier(0); } while (0)

__device__ __forceinline__ float sigm(float x) {
  float p = __expf(-fabsf(x));
  float r = 1.f / (1.f + p);
  return x >= 0.f ? r : 1.f - r;
}
__device__ __forceinline__ float tanh_(float x) {
  float p = __expf(-2.f * fabsf(x));
  float r = (1.f - p) / (1.f + p);
  return x >= 0.f ? r : -r;
}

// async global->LDS, 16B per lane; LDS dest is wave-uniform base + lane*16
__device__ __forceinline__ void gll16(const f16* g, f16* l) {
  __builtin_amdgcn_global_load_lds(
      (const __attribute__((address_space(1))) unsigned int*)g,
      (__attribute__((address_space(3))) unsigned int*)l, 16, 0, 0);
}

// ---------------- prep ----------------

// 4-way K-split partial sums-of-squares (wh: K=1900=4x475; wx/wmx: seg 0 only)
__global__ void k_norms_p(const float* __restrict__ wh, const float* __restrict__ wx,
                          const float* __restrict__ wmh, const float* __restrict__ wmx,
                          float* __restrict__ part) {
  int seg = blockIdx.x & 3;
  int tid = (blockIdx.x >> 2) * 256 + threadIdx.x;   // 0..19199
  float s = 0.f;
  if (tid < 7600) {
    int k0 = seg * 475;
    for (int k = k0; k < k0 + 475; k++) { float v = wh[(size_t)k * 7600 + tid]; s += v * v; }
  } else if (tid < 15200) {
    if (seg == 0) {
      int n = tid - 7600;
      for (int e = 0; e < EMB_; e++) { float v = wx[(size_t)e * 7600 + n]; s += v * v; }
    }
  } else if (tid < 17100) {
    int n = tid - 15200; int k0 = seg * 475;
    for (int k = k0; k < k0 + 475; k++) { float v = wmh[(size_t)k * H_ + n]; s += v * v; }
  } else if (tid < 19000) {
    if (seg == 0) {
      int n = tid - 17100;
      for (int e = 0; e < EMB_; e++) { float v = wmx[(size_t)e * H_ + n]; s += v * v; }
    }
  }
  if (tid < 19000) part[(size_t)seg * 19000 + tid] = s;
}

__global__ void k_norms_f(const float* __restrict__ part,
                          const float* __restrict__ gh, const float* __restrict__ gx,
                          const float* __restrict__ gmh, const float* __restrict__ gmx,
                          float* __restrict__ inv_wh, float* __restrict__ inv_wx,
                          float* __restrict__ inv_wmh, float* __restrict__ inv_wmx) {
  int tid = blockIdx.x * 256 + threadIdx.x;
  if (tid >= 19000) return;
  float s = part[tid] + part[19000 + tid] + part[38000 + tid] + part[57000 + tid];
  float r = rsqrtf(fmaxf(s, 1e-12f));
  if (tid < 7600)        inv_wh[tid] = gh[tid] * r;
  else if (tid < 15200)  { int n = tid - 7600;  inv_wx[n]  = gx[n]  * r; }
  else if (tid < 17100)  { int n = tid - 15200; inv_wmh[n] = gmh[n] * r; }
  else                   { int n = tid - 17100; inv_wmx[n] = gmx[n] * r; }
}

// WmhS fragment-swizzled: group (c,kb): element (n=16c+nl, k=32kb+kl)
__global__ void k_wmhS(const float* __restrict__ wmh, const float* __restrict__ inv,
                       f16* __restrict__ WmhS) {
  int i = blockIdx.x * 256 + threadIdx.x;
  if (i >= 1920 * 1920) return;
  int n = i % 1920, k = i / 1920;
  float v = (n < H_ && k < H_) ? wmh[(size_t)k * H_ + n] * inv[n] : 0.f;
  int c = n >> 4, nl = n & 15, kb = k >> 5, kl = k & 31;
  WmhS[(((size_t)c * NKA + kb) * 512) + (nl + 16 * (kl >> 3)) * 8 + (kl & 7)] = (f16)v;
}

// WhS fragment-swizzled, gate-grouped: group (q*4+g, kb); K-ext rows carry wx/b
__global__ void k_whS(const float* __restrict__ wh, const float* __restrict__ wx,
                      const float* __restrict__ bias,
                      const float* __restrict__ inv_wh, const float* __restrict__ inv_wx,
                      f16* __restrict__ WhS) {
  int i = blockIdx.x * 256 + threadIdx.x;
  if (i >= 7600 * 1952) return;
  int col = i % 7600, k = i / 7600;
  float v = 0.f;
  if (k < H_)                        v = wh[(size_t)k * 7600 + col] * inv_wh[col];
  else if (k >= HP && k < HP + EMB_) v = wx[(size_t)(k - HP) * 7600 + col] * inv_wx[col];
  else if (k == HP + EMB_)           v = bias[col];
  int g = col / H_, n = col % H_;
  int q = n >> 4, nl = n & 15, kb = k >> 5, kl = k & 31;
  WhS[(((size_t)(q * 4 + g) * NKB + kb) * 512) + (nl + 16 * (kl >> 3)) * 8 + (kl & 7)] = (f16)v;
}

__global__ void k_wmxT(const float* __restrict__ wmx, const float* __restrict__ inv_wmx,
                       f16* __restrict__ wmxT) {
  int i = blockIdx.x * 256 + threadIdx.x;
  if (i >= HP * 32) return;
  int n = i >> 5, k = i & 31;
  float v = (k < EMB_ && n < H_) ? wmx[(size_t)k * H_ + n] * inv_wmx[n] : 0.f;
  wmxT[i] = (f16)v;
}

__global__ void k_lens(const int* __restrict__ ex, const int* __restrict__ lx,
                       const int* __restrict__ rx, int* __restrict__ sel) {
  int s = threadIdx.x;
  int el = 0; for (int i = 0; i < 25; i++) el += (ex[s * 25 + i] != 26);
  int ll = 0; for (int i = 0; i < 64; i++) ll += (lx[s * 64 + i] != 26);
  int rl = 0; for (int i = 0; i < 64; i++) rl += (rx[s * 64 + i] != 26);
  ll = ll < 1 ? 1 : ll;  rl = rl < 1 ? 1 : rl;
  int tl = el + ll + rl;
  int ti = tl - 1; ti = ti < 0 ? 0 : (ti > 152 ? 152 : ti);
  int ei = el - 1; ei = ei < 0 ? 0 : (ei > 24 ? 24 : ei);
  sel[s] = ti; sel[256 + s] = ei;
}

__global__ void k_init(f16* __restrict__ h0, f16* __restrict__ h1, float* __restrict__ c) {
  int i = blockIdx.x * 256 + threadIdx.x;
  if (i < NR * HP) { h0[i] = (f16)0.f; h1[i] = (f16)0.f; c[i] = 0.f; }
}

// xe16[t][row][32]: cols 0..9 = embed[token], col 10 = 1.0 (bias), rest 0
__global__ void k_xe16(const int* __restrict__ totx, const int* __restrict__ epix,
                       const float* __restrict__ embed, f16* __restrict__ xe16) {
  int i = blockIdx.x * blockDim.x + threadIdx.x;
  if (i >= TT * NR) return;
  int t = i / NR, r = i % NR;
  int tok = -1;
  if (r < 256) tok = totx[r * TT + t];
  else if (t < TE) tok = epix[(r - 256) * TE + t];
  f16* o = xe16 + (size_t)i * 32;
  #pragma unroll
  for (int e = 0; e < EMB_; e++) o[e] = (f16)(tok >= 0 ? embed[tok * EMB_ + e] : 0.f);
  o[10] = (f16)1.f;
  #pragma unroll
  for (int e = 11; e < 32; e++) o[e] = (f16)0.f;
}

// ---------------- recurrence ----------------

// Phase A: block = (ct, cbh, rg); 4 waves x 16 rows x 32 cols (2 cb).
// Counted-vmcnt 2-buffer pipeline; 4 blocks/CU target.
// Per-wave VMEM per group: S = n/2 gll (4 full / 2 tail), A = n loads (8/4).
__global__ __launch_bounds__(256, 4)
void k_stepA(const f16* __restrict__ hS, const f16* __restrict__ WmhS,
             const f16* __restrict__ xe16_t, const f16* __restrict__ wmxT,
             f16* __restrict__ mS, int rgc) {
  __shared__ __align__(16) f16 Bb[2][8][2][512];   // 32 KB
  const int lane = threadIdx.x & 63, wid = threadIdx.x >> 6;
  const int bi = blockIdx.x;
  const int x = bi & 7, mm = bi >> 3;
  const int rg = mm % rgc, rem = mm / rgc;
  const int cbh = rem & 1, chi = rem >> 1;
  const int ct = chi * 8 + x;                      // ct%8 == x (XCD-stable)
  if (ct >= 30) return;
  const int rtile = rg * 4 + wid;
  const int r0 = rtile * 16;
  const int l16 = lane & 15, l4 = lane >> 4;

  const f16* Abase = hS   + (size_t)rtile * NKA * 512 + lane * 8;
  const f16* Bglob = WmhS + (size_t)(ct * 4 + cbh * 2) * NKA * 512 + lane * 8;

  // xm = xe16 @ wmxT (once per wave, this block's 2 column-16-groups)
  f32x4 xm[2];
  {
    half8 xa = *(const half8*)(xe16_t + (size_t)(r0 + l16) * 32 + l4 * 8);
    #pragma unroll
    for (int cb = 0; cb < 2; cb++) {
      half8 xb = *(const half8*)(wmxT + (size_t)(ct * 64 + (cbh * 2 + cb) * 16 + l16) * 32 + l4 * 8);
      f32x4 z = {0.f, 0.f, 0.f, 0.f};
      xm[cb] = __builtin_amdgcn_mfma_f32_16x16x32_f16(xa, xb, z, 0, 0, 0);
    }
  }
  WAITV(0);   // clean vmcnt baseline for the counted region

  half8 Areg[2][8];
  f32x4 acc[2];
  #pragma unroll
  for (int cb = 0; cb < 2; cb++) { f32x4 z = {0.f, 0.f, 0.f, 0.f}; acc[cb] = z; }

#define STAGE_A(g, buf, n_) { _Pragma("unroll") for (int q_ = 0; q_ < ((n_) >> 1); q_++) { \
    int p_ = wid * ((n_) >> 1) + q_; int kbl_ = p_ >> 1, cb_ = p_ & 1; \
    gll16(Bglob + ((size_t)cb_ * NKA + (g) * 8 + kbl_) * 512, &Bb[buf][kbl_][cb_][0]); } }
#define LOADA_A(g, buf, n_) { _Pragma("unroll") for (int kk_ = 0; kk_ < 8; kk_++) if (kk_ < (n_)) \
    Areg[buf][kk_] = *(const half8*)(Abase + (size_t)((g) * 8 + kk_) * 512); }
#define COMP_A(g, buf, n_) { _Pragma("unroll") for (int kk_ = 0; kk_ < 8; kk_++) if (kk_ < (n_)) { \
    half8 b0_ = *(const half8*)&Bb[buf][kk_][0][lane * 8]; \
    half8 b1_ = *(const half8*)&Bb[buf][kk_][1][lane * 8]; \
    acc[0] = __builtin_amdgcn_mfma_f32_16x16x32_f16(Areg[buf][kk_], b0_, acc[0], 0, 0, 0); \
    acc[1] = __builtin_amdgcn_mfma_f32_16x16x32_f16(Areg[buf][kk_], b1_, acc[1], 0, 0, 0); } }

  // prologue: group 0 in flight (12 outstanding/wave)
  STAGE_A(0, 0, 8); LOADA_A(0, 0, 8);
  #pragma unroll
  for (int g = 0; g < 8; g++) {
    const int nn = (g == 7) ? 4 : 8;
    BARR;                                   // buf[(g+1)&1] free (readers done)
    if (g < 7) {
      const int nn1 = (g == 6) ? 4 : 8;
      STAGE_A(g + 1, (g + 1) & 1, nn1); LOADA_A(g + 1, (g + 1) & 1, nn1);
    }
    // retire S(g)+A(g): out = 12 + [next-group issue] -> wait leaves next in flight
    if (g < 6)       WAITV(12);
    else if (g == 6) WAITV(6);
    else             WAITV(0);
    BARR;                                   // all waves' S(g) landed
    COMP_A(g, g & 1, nn);
  }
#undef STAGE_A
#undef LOADA_A
#undef COMP_A

  // epilogue: m = hm * xm, written in stepB's A-fragment order.
  const int q4 = lane >> 4, c16 = lane & 15;
  const int kb = ct * 2 + cbh;
  #pragma unroll
  for (int cb = 0; cb < 2; cb++) {
    int klane = cb * 16 + c16;
    int lf = (klane >> 3) * 16;
    int sub = c16 & 7;
    f16* dst = mS + ((size_t)rtile * NKB + kb) * 512 + sub;
    #pragma unroll
    for (int q = 0; q < 4; q++) {
      int rl = q4 * 4 + q;
      dst[(rl + lf) * 8] = (f16)(acc[cb][q] * xm[cb][q]);
    }
  }
  if (ct == 0 && cbh == 0) {  // K-extension chunk 60 = xe16 row (contiguous copy)
    f16* dst = mS + ((size_t)rtile * NKB + 60) * 512 + lane * 8;
    *(half8*)dst = *(const half8*)(xe16_t + (size_t)(r0 + l16) * 32 + l4 * 8);
  }
}

// Phase B: block = (colq, rg); 4 waves x one 16-row rtile (64 rows/block).
// Counted-vmcnt 2-buffer pipeline; 4 blocks/CU target.
// Per-wave VMEM per group: S = n gll (4 full / 1 tail), A = n loads.
__global__ __launch_bounds__(256, 4)
void k_stepB(const f16* __restrict__ mS, const f16* __restrict__ WhS,
             float* __restrict__ c, f16* __restrict__ houtS,
             float* __restrict__ selH, const int* __restrict__ sel, int t, int rgc) {
  __shared__ __align__(16) f16 Bb[2][4][4][512];   // 32 KB
  const int lane = threadIdx.x & 63, wid = threadIdx.x >> 6;
  const int bi = blockIdx.x;
  const int x = bi & 7, mm = bi >> 3;
  const int rg = mm % rgc, chi = mm / rgc;
  const int colq = chi * 8 + x;                    // colq%8 == x (XCD-stable)
  if (colq >= 119) return;
  const int rtile = rg * 4 + wid;
  const int r0 = rtile * 16;

  const f16* Abase = mS  + (size_t)rtile * NKB * 512 + lane * 8;
  const f16* Bglob = WhS + (size_t)(colq * 4) * NKB * 512 + lane * 8;

  half8 Areg[2][4];
  f32x4 acc[4];
  #pragma unroll
  for (int b = 0; b < 4; b++) { f32x4 z = {0.f, 0.f, 0.f, 0.f}; acc[b] = z; }

#define STAGE_B(g, buf, n_) { _Pragma("unroll") for (int q_ = 0; q_ < (n_); q_++) { \
    int p_ = wid * (n_) + q_; int kbl_ = p_ >> 2, gg_ = p_ & 3; \
    gll16(Bglob + ((size_t)gg_ * NKB + (g) * 4 + kbl_) * 512, &Bb[buf][kbl_][gg_][0]); } }
#define LOADA_B(g, buf, n_) { _Pragma("unroll") for (int kk_ = 0; kk_ < 4; kk_++) if (kk_ < (n_)) \
    Areg[buf][kk_] = *(const half8*)(Abase + (size_t)((g) * 4 + kk_) * 512); }
#define COMP_B(g, buf, n_) { _Pragma("unroll") for (int kk_ = 0; kk_ < 4; kk_++) if (kk_ < (n_)) { \
    half8 b0_ = *(const half8*)&Bb[buf][kk_][0][lane * 8]; \
    half8 b1_ = *(const half8*)&Bb[buf][kk_][1][lane * 8]; \
    half8 b2_ = *(const half8*)&Bb[buf][kk_][2][lane * 8]; \
    half8 b3_ = *(const half8*)&Bb[buf][kk_][3][lane * 8]; \
    acc[0] = __builtin_amdgcn_mfma_f32_16x16x32_f16(Areg[buf][kk_], b0_, acc[0], 0, 0, 0); \
    acc[1] = __builtin_amdgcn_mfma_f32_16x16x32_f16(Areg[buf][kk_], b1_, acc[1], 0, 0, 0); \
    acc[2] = __builtin_amdgcn_mfma_f32_16x16x32_f16(Areg[buf][kk_], b2_, acc[2], 0, 0, 0); \
    acc[3] = __builtin_amdgcn_mfma_f32_16x16x32_f16(Areg[buf][kk_], b3_, acc[3], 0, 0, 0); } }

  // prologue: group 0 in flight (8 outstanding/wave)
  STAGE_B(0, 0, 4); LOADA_B(0, 0, 4);
  #pragma unroll
  for (int g = 0; g < 16; g++) {
    const int nn = (g == 15) ? 1 : 4;
    BARR;
    if (g < 15) {
      const int nn1 = (g == 14) ? 1 : 4;
      STAGE_B(g + 1, (g + 1) & 1, nn1); LOADA_B(g + 1, (g + 1) & 1, nn1);
    }
    if (g < 14)       WAITV(8);
    else if (g == 14) WAITV(2);
    else              WAITV(0);
    BARR;
    COMP_B(g, g & 1, nn);
  }
#undef STAGE_B
#undef LOADA_B
#undef COMP_B

  const int q4 = lane >> 4, c16 = lane & 15;
  const int j = colq * 16 + c16;
  const bool valid = j < H_;
  const int kbh = colq >> 1;
  const int lfh = ((((colq & 1) * 16 + c16) >> 3)) * 16;
  const int subh = c16 & 7;
  f16* hdst = houtS + ((size_t)rtile * NKA + kbh) * 512 + subh;
  #pragma unroll
  for (int q = 0; q < 4; q++) {
    int rl = q4 * 4 + q;
    int row = r0 + rl;
    if (valid) {
      size_t idx = (size_t)row * HP + j;
      float cold = c[idx];
      float iz = acc[0][q], fz = acc[1][q];
      float oz = acc[2][q], uz = acc[3][q];
      float cn = sigm(fz) * cold + sigm(iz) * tanh_(uz);
      float hv = sigm(oz) * tanh_(cn);
      c[idx] = cn;
      hdst[(rl + lfh) * 8] = (f16)hv;
      if (t == sel[row]) selH[idx] = hv;
    }
  }
}

// ---------------- classifier ----------------

__global__ void k_xqS(const float* __restrict__ selH, const float* __restrict__ g1,
                      const float* __restrict__ be1, const float* __restrict__ mu1,
                      const float* __restrict__ var1, f16* __restrict__ xqS) {
  int i = blockIdx.x * 256 + threadIdx.x;
  if (i >= 256 * 3840) return;
  int k = i % 3840, s = i / 3840;
  float v = 0.f; bool have = false;
  if (k < H_)            { v = selH[(size_t)s * HP + k]; have = true; }
  else if (k < 2 * H_)   { v = selH[(size_t)(256 + s) * HP + (k - H_)]; have = true; }
  float q = 0.f;
  if (have) {
    float lr = v < 0.f ? 0.3f * v : v;
    q = (lr - mu1[k]) * rsqrtf(var1[k] + 1e-3f) * g1[k] + be1[k];
  }
  int rtile = s >> 4, sl = s & 15, kb = k >> 5, kl = k & 31;
  xqS[(((size_t)rtile * NKF + kb) * 512) + (sl + 16 * (kl >> 3)) * 8 + (kl & 7)] = (f16)q;
}

__global__ void k_w1S(const float* __restrict__ W1, f16* __restrict__ W1S) {
  int i = blockIdx.x * 256 + threadIdx.x;
  if (i >= 384 * 3840) return;
  int col = i % 384, k = i / 384;
  float v = (col < 380 && k < 2 * H_) ? W1[(size_t)k * 380 + col] : 0.f;
  int cg = col >> 4, nl = col & 15, kb = k >> 5, kl = k & 31;
  W1S[(((size_t)cg * NKF + kb) * 512) + (nl + 16 * (kl >> 3)) * 8 + (kl & 7)] = (f16)v;
}

// fc1: wave = 16 rows x 64 cols, K=3840 (120 chunks), branch-free pipeline
__global__ __launch_bounds__(256)
void k_fc1(const f16* __restrict__ xqS, const f16* __restrict__ W1S,
           const float* __restrict__ b1, float* __restrict__ z1) {
  const int lane = threadIdx.x & 63, wid = threadIdx.x >> 6;
  const int ct = blockIdx.x % 6, rg = blockIdx.x / 6;
  const int rtile = rg * 4 + wid;
  const int r0 = rtile * 16;

  const f16* Abase = xqS + (size_t)rtile * NKF * 512 + lane * 8;
  const f16* Bbase = W1S + (size_t)(ct * 4) * NKF * 512 + lane * 8;

  half8 fa0, fa1, fa2, fa3;
  half8 fb0[4], fb1[4], fb2[4], fb3[4];
  f32x4 acc[4];
  #pragma unroll
  for (int cb = 0; cb < 4; cb++) { f32x4 z = {0.f, 0.f, 0.f, 0.f}; acc[cb] = z; }

#define LDA_F(d, kb)  d = *(const half8*)(Abase + (size_t)(kb) * 512)
#define LDB_F(d, kb)  { _Pragma("unroll") for (int cb = 0; cb < 4; cb++) \
    d[cb] = *(const half8*)(Bbase + ((size_t)cb * NKF + (kb)) * 512); }
#define MMA_F(fa, fb) { _Pragma("unroll") for (int cb = 0; cb < 4; cb++) \
    acc[cb] = __builtin_amdgcn_mfma_f32_16x16x32_f16(fa, fb[cb], acc[cb], 0, 0, 0); }

  LDA_F(fa0, 0); LDB_F(fb0, 0);
  LDA_F(fa1, 1); LDB_F(fb1, 1);
  LDA_F(fa2, 2); LDB_F(fb2, 2);
  for (int base = 0; base < 116; base += 4) {
    LDA_F(fa3, base + 3); LDB_F(fb3, base + 3);
    MMA_F(fa0, fb0);
    LDA_F(fa0, base + 4); LDB_F(fb0, base + 4);
    MMA_F(fa1, fb1);
    LDA_F(fa1, base + 5); LDB_F(fb1, base + 5);
    MMA_F(fa2, fb2);
    LDA_F(fa2, base + 6); LDB_F(fb2, base + 6);
    MMA_F(fa3, fb3);
  }
  LDA_F(fa3, 119); LDB_F(fb3, 119);
  MMA_F(fa0, fb0);   // 116
  MMA_F(fa1, fb1);   // 117
  MMA_F(fa2, fb2);   // 118
  MMA_F(fa3, fb3);   // 119
#undef LDA_F
#undef LDB_F
#undef MMA_F

  const int q4 = lane >> 4, c16 = lane & 15;
  #pragma unroll
  for (int cb = 0; cb < 4; cb++)
    #pragma unroll
    for (int q = 0; q < 4; q++) {
      int row = r0 + q4 * 4 + q;
      int col = ct * 64 + cb * 16 + c16;
      float bias = (col < 380) ? b1[col] : 0.f;
      z1[(size_t)row * FCN + col] = acc[cb][q] + bias;
    }
}

__global__ void k_fc2(const float* __restrict__ z1, const float* __restrict__ g2,
                      const float* __restrict__ be2, const float* __restrict__ mu2,
                      const float* __restrict__ var2, const float* __restrict__ W2,
                      const float* __restrict__ b2, float* __restrict__ out) {
  int s = threadIdx.x;
  float a = 0.f;
  for (int jj = 0; jj < 380; jj++) {
    float v = z1[(size_t)s * FCN + jj];
    float lr = v < 0.f ? 0.3f * v : v;
    float q = (lr - mu2[jj]) * rsqrtf(var2[jj] + 1e-3f) * g2[jj] + be2[jj];
    a += q * W2[jj];
  }
  out[s] = a + b2[0];
}

// ---------------- host ----------------

extern "C" void kernel_launch(void* const* d_in, const int* in_sizes, int n_in,
                              void* d_out, int out_size, void* d_ws, size_t ws_size,
                              hipStream_t stream) {
  const int*   epix  = (const int*)d_in[0];
  const int*   lx    = (const int*)d_in[1];
  const int*   rx    = (const int*)d_in[2];
  const int*   totx  = (const int*)d_in[3];
  const float* embed = (const float*)d_in[4];
  const float* wx    = (const float*)d_in[5];
  const float* wh    = (const float*)d_in[6];
  const float* wmx   = (const float*)d_in[7];
  const float* wmh   = (const float*)d_in[8];
  const float* bb    = (const float*)d_in[9];
  const float* gx    = (const float*)d_in[10];
  const float* gh    = (const float*)d_in[11];
  const float* gmx   = (const float*)d_in[12];
  const float* gmh   = (const float*)d_in[13];
  const float* bn1g  = (const float*)d_in[14];
  const float* bn1b  = (const float*)d_in[15];
  const float* bn1m  = (const float*)d_in[16];
  const float* bn1v  = (const float*)d_in[17];
  const float* W1    = (const float*)d_in[18];
  const float* b1    = (const float*)d_in[19];
  const float* bn2g  = (const float*)d_in[20];
  const float* bn2b  = (const float*)d_in[21];
  const float* bn2m  = (const float*)d_in[22];
  const float* bn2v  = (const float*)d_in[23];
  const float* W2    = (const float*)d_in[24];
  const float* b2v   = (const float*)d_in[25];

  char* base = (char*)d_ws;
  size_t off = 0;
  auto alloc = [&](size_t n) { char* p = base + off; off = (off + n + 255) & ~(size_t)255; return p; };

  f16*   WmhS   = (f16*)  alloc((size_t)120 * NKA * 512 * 2);
  f16*   WhS    = (f16*)  alloc((size_t)119 * 4 * NKB * 512 * 2);
  f16*   wmxT   = (f16*)  alloc((size_t)HP * 32 * 2);
  f16*   xe16   = (f16*)  alloc((size_t)TT * NR * 32 * 2);
  f16*   h0S    = (f16*)  alloc((size_t)32 * NKA * 512 * 2);
  f16*   h1S    = (f16*)  alloc((size_t)32 * NKA * 512 * 2);
  f16*   mS     = (f16*)  alloc((size_t)32 * NKB * 512 * 2);
  float* cst    = (float*)alloc((size_t)NR * HP * 4);
  float* selH   = (float*)alloc((size_t)NR * HP * 4);
  int*   sel    = (int*)  alloc((size_t)NR * 4);
  float* inv_wh = (float*)alloc(7600 * 4);
  float* inv_wx = (float*)alloc(7600 * 4);
  float* inv_wmh= (float*)alloc(1900 * 4);
  float* inv_wmx= (float*)alloc(1900 * 4);
  float* npart  = (float*)alloc((size_t)4 * 19000 * 4);
  f16*   xqS    = (f16*)  alloc((size_t)16 * NKF * 512 * 2);
  f16*   W1S    = (f16*)  alloc((size_t)24 * NKF * 512 * 2);
  float* z1     = (float*)alloc((size_t)256 * FCN * 4);
  (void)in_sizes; (void)n_in; (void)out_size; (void)ws_size;

  hipLaunchKernelGGL(k_norms_p, dim3(300), dim3(256), 0, stream, wh, wx, wmh, wmx, npart);
  hipLaunchKernelGGL(k_norms_f, dim3(75), dim3(256), 0, stream,
                     npart, gh, gx, gmh, gmx, inv_wh, inv_wx, inv_wmh, inv_wmx);
  hipLaunchKernelGGL(k_wmhS, dim3((1920 * 1920 + 255) / 256), dim3(256), 0, stream,
                     wmh, inv_wmh, WmhS);
  hipLaunchKernelGGL(k_whS, dim3((7600 * 1952 + 255) / 256), dim3(256), 0, stream,
                     wh, wx, bb, inv_wh, inv_wx, WhS);
  hipLaunchKernelGGL(k_wmxT, dim3((HP * 32 + 255) / 256), dim3(256), 0, stream,
                     wmx, inv_wmx, wmxT);
  hipLaunchKernelGGL(k_lens, dim3(1), dim3(256), 0, stream, epix, lx, rx, sel);
  hipLaunchKernelGGL(k_init, dim3((NR * HP + 255) / 256), dim3(256), 0, stream,
                     h0S, h1S, cst);
  hipLaunchKernelGGL(k_xe16, dim3((TT * NR + 255) / 256), dim3(256), 0, stream,
                     totx, epix, embed, xe16);

  for (int t = 0; t < TT; t++) {
    int Mt = (t < TE) ? NR : 256;
    const f16* hin = (t & 1) ? h1S : h0S;
    f16*       ho  = (t & 1) ? h0S : h1S;
    int rgcA = Mt / 64;   // stepA row-groups of 64 rows
    int rgcB = Mt / 64;   // stepB row-groups of 64 rows
    hipLaunchKernelGGL(k_stepA, dim3(64 * rgcA), dim3(256), 0, stream,
                       hin, WmhS, xe16 + (size_t)t * NR * 32, wmxT, mS, rgcA);
    hipLaunchKernelGGL(k_stepB, dim3(8 * rgcB * 15), dim3(256), 0, stream,
                       mS, WhS, cst, ho, selH, sel, t, rgcB);
  }

  hipLaunchKernelGGL(k_xqS, dim3((256 * 3840 + 255) / 256), dim3(256), 0, stream,
                     selH, bn1g, bn1b, bn1m, bn1v, xqS);
  hipLaunchKernelGGL(k_w1S, dim3((384 * 3840 + 255) / 256), dim3(256), 0, stream, W1, W1S);
  hipLaunchKernelGGL(k_fc1, dim3(24), dim3(256), 0, stream, xqS, W1S, b1, z1);
  hipLaunchKernelGGL(k_fc2, dim3(1), dim3(256), 0, stream,
                     z1, bn2g, bn2b, bn2m, bn2v, W2, b2v, (float*)d_out);
}